// Round 11
// baseline (605.761 us; speedup 1.0000x reference)
//
#include <hip/hip_runtime.h>
#include <hip/hip_bf16.h>

#define NN 50000
#define NE 800000
#define DD 256
#define OO 32
#define NSL ((size_t)NN * 32)  // ushorts per 32-col slab

typedef __attribute__((ext_vector_type(8))) short short8;
typedef __attribute__((ext_vector_type(4))) float float4v;

#define AS1 __attribute__((address_space(1)))
#define AS3 __attribute__((address_space(3)))

__device__ __forceinline__ float lo16f(unsigned int u) {
    union { unsigned int i; float f; } x; x.i = u << 16; return x.f;
}
__device__ __forceinline__ float hi16f(unsigned int u) {
    union { unsigned int i; float f; } x; x.i = u & 0xFFFF0000u; return x.f;
}
__device__ __forceinline__ unsigned short f2b(float f) {
    union { float f; unsigned int i; } x;
    x.f = f;
    unsigned int r = x.i + 0x7FFFu + ((x.i >> 16) & 1u);  // RNE
    return (unsigned short)(r >> 16);
}

// ---------------------------------------------------------------------------
// CSR build
// ---------------------------------------------------------------------------
__global__ void count_kernel(const int* __restrict__ row, int* __restrict__ cnt, int E) {
    int e = blockIdx.x * blockDim.x + threadIdx.x;
    if (e < E) atomicAdd(&cnt[row[e]], 1);
}

__global__ __launch_bounds__(256) void block_sums(const int* __restrict__ cnt,
                                                  int* __restrict__ bsum, int N) {
    __shared__ int s[256];
    int idx = blockIdx.x * 256 + threadIdx.x;
    s[threadIdx.x] = (idx < N) ? cnt[idx] : 0;
    __syncthreads();
    for (int o = 128; o > 0; o >>= 1) {
        if (threadIdx.x < o) s[threadIdx.x] += s[threadIdx.x + o];
        __syncthreads();
    }
    if (threadIdx.x == 0) bsum[blockIdx.x] = s[0];
}

__global__ __launch_bounds__(256) void scan_bsums(const int* __restrict__ bsum,
                                                  int* __restrict__ bpre, int nb) {
    __shared__ int s[256];
    int t = threadIdx.x;
    int v0 = (t < nb) ? bsum[t] : 0;
    s[t] = v0;
    __syncthreads();
    for (int o = 1; o < 256; o <<= 1) {
        int v = (t >= o) ? s[t - o] : 0;
        __syncthreads();
        s[t] += v;
        __syncthreads();
    }
    if (t < nb) bpre[t] = s[t] - v0;  // exclusive prefix
}

__global__ __launch_bounds__(256) void fill_rowptr(const int* __restrict__ cnt,
                                                   const int* __restrict__ bpre,
                                                   int* __restrict__ row_ptr,
                                                   int* __restrict__ cursor,
                                                   float* __restrict__ dinv, int N, int E) {
    __shared__ int s[256];
    int t = threadIdx.x;
    int idx = blockIdx.x * 256 + t;
    int c = (idx < N) ? cnt[idx] : 0;
    s[t] = c;
    __syncthreads();
    for (int o = 1; o < 256; o <<= 1) {
        int v = (t >= o) ? s[t - o] : 0;
        __syncthreads();
        s[t] += v;
        __syncthreads();
    }
    int excl = bpre[blockIdx.x] + s[t] - c;
    if (idx < N) {
        row_ptr[idx] = excl;
        cursor[idx] = excl;
        dinv[idx] = rsqrtf((float)(c + 1));  // +1 self-loop
    }
    if (idx == N) row_ptr[N] = E;
}

// scatter also precomputes edge-aligned dc = dinv[col] (kills random dinv gathers in agg)
__global__ void scatter_kernel(const int* __restrict__ row, const int* __restrict__ col,
                               int* __restrict__ cursor, const float* __restrict__ dinv,
                               int* __restrict__ csr_col, float* __restrict__ csr_dc, int E) {
    int e = blockIdx.x * blockDim.x + threadIdx.x;
    if (e < E) {
        int c = col[e];
        int p = atomicAdd(&cursor[row[e]], 1);
        csr_col[p] = c;
        csr_dc[p] = dinv[c];
    }
}

// ---------------------------------------------------------------------------
// cast x -> bf16 in SLAB-MAJOR layout: Xs[slab][node][32], slab = col>>5.
// Block = 64 nodes; writes fully contiguous per slab-row-group.
// ---------------------------------------------------------------------------
__global__ __launch_bounds__(256) void cast_x_slab(const float* __restrict__ x,
                                                   unsigned short* __restrict__ xs) {
    int nb0 = blockIdx.x * 64;
#pragma unroll
    for (int i = 0; i < 8; ++i) {
        int id = i * 256 + threadIdx.x;   // 0..2047 = 8 slabs x 64 rows x 4 parts
        int slab = id >> 8;
        int rw = (id >> 2) & 63;
        int part = id & 3;
        int node = nb0 + rw;
        if (node < NN) {
            const float* src = x + (size_t)node * 256 + slab * 32 + part * 8;
            unsigned short o[8];
#pragma unroll
            for (int q = 0; q < 8; ++q) o[q] = f2b(src[q]);
            *(short8*)(xs + (size_t)slab * NSL + (size_t)node * 32 + part * 8) = *(short8*)o;
        }
    }
}

// ---------------------------------------------------------------------------
// Weight packing (fragment-order, unchanged): element (k, n) ->
//   (k>>5)*8192 + (n>>4)*512 + (((k&31)>>3)*16 + (n&15))*8 + (k&7)
// ---------------------------------------------------------------------------
__device__ __forceinline__ int pack_idx(int k, int n) {
    return (k >> 5) * 8192 + (n >> 4) * 512 + (((k & 31) >> 3) * 16 + (n & 15)) * 8 + (k & 7);
}

__global__ __launch_bounds__(256) void cast_w2(const float* __restrict__ W2,
                                               unsigned short* __restrict__ Wt2) {
    int n = blockIdx.x;  // 32 blocks
    int k = threadIdx.x;
    Wt2[n * 256 + k] = f2b(W2[k * 32 + n]);
}

__global__ __launch_bounds__(256) void compose_wc(const float* __restrict__ W0,
                                                  const float* __restrict__ Wn0,
                                                  const float* __restrict__ W1,
                                                  const float* __restrict__ Wn1,
                                                  unsigned short* __restrict__ Wp0,
                                                  unsigned short* __restrict__ Wp1) {
    const float* W  = blockIdx.y ? W1 : W0;
    const float* Wn = blockIdx.y ? Wn1 : Wn0;
    unsigned short* T = blockIdx.y ? Wp1 : Wp0;
    __shared__ float wrow[256];
    int k = blockIdx.x, n = threadIdx.x;
    float wkn = W[k * 256 + n];
    wrow[n] = wkn;
    T[pack_idx(k, n)] = f2b(wkn);
    __syncthreads();
    float s = 0.f;
#pragma unroll 8
    for (int m = 0; m < 256; ++m) s = fmaf(wrow[m], Wn[m * 256 + n], s);
    T[pack_idx(k + 256, n)] = f2b(s);
}

__global__ __launch_bounds__(256) void compose_bc(const float* __restrict__ b0_,
                                                  const float* __restrict__ Wn0,
                                                  const float* __restrict__ bn0,
                                                  const float* __restrict__ b1_,
                                                  const float* __restrict__ Wn1,
                                                  const float* __restrict__ bn1,
                                                  float* __restrict__ bc0,
                                                  float* __restrict__ bc1) {
    const float* b  = blockIdx.y ? b1_ : b0_;
    const float* Wn = blockIdx.y ? Wn1 : Wn0;
    const float* bn = blockIdx.y ? bn1 : bn0;
    float* bc = blockIdx.y ? bc1 : bc0;
    int n = threadIdx.x;
    float s = bn[n];
    for (int m = 0; m < 256; ++m) s = fmaf(b[m], Wn[m * 256 + n], s);
    bc[n] = s;
}

// ---------------------------------------------------------------------------
// Slab-pass aggregation: G = P @ A, slab-major in/out.
// grid (N/4, 8): blockIdx.y = slab (3.2 MB, fits per-XCD L2; y-major dispatch
// keeps concurrent blocks on the same slab). Wave per node; per load instr
// 16 neighbors x 64B (lane: part=lane&3 -> 8 cols, rep=lane>>2 -> neighbor).
// Replica-reduce via shfl_xor(4,8,16,32). pv written by slab 0.
// ---------------------------------------------------------------------------
__global__ __launch_bounds__(256) void agg_g_slab(const unsigned short* __restrict__ A,
                                                  const float* __restrict__ dinv,
                                                  const int* __restrict__ row_ptr,
                                                  const int* __restrict__ csr_col,
                                                  const float* __restrict__ csr_dc,
                                                  unsigned short* __restrict__ G,
                                                  float* __restrict__ pv) {
    int wave = threadIdx.x >> 6, lane = threadIdx.x & 63;
    int part = lane & 3, rep = lane >> 2;
    int v = blockIdx.x * 4 + wave;
    int s = blockIdx.y;
    float dv = dinv[v];
    const unsigned short* As = A + (size_t)s * NSL;
    unsigned short* Gs = G + (size_t)s * NSL;

    float acc[8] = {0.f, 0.f, 0.f, 0.f, 0.f, 0.f, 0.f, 0.f};
    float sdc = 0.f;

    int st = row_ptr[v], en = row_ptr[v + 1];
    for (int b0 = st; b0 < en; b0 += 64) {
        int mm = en - b0;
        if (mm > 64) mm = 64;
        int c = 0;
        float dc = 0.f;
        if (lane < mm) { c = csr_col[b0 + lane]; dc = csr_dc[b0 + lane]; }
        sdc += dc;
        for (int j = 0; j < mm; j += 16) {
            int idx = j + rep;                    // lanes >= mm carry c=0, dc=0
            int ci = __shfl(c, idx);
            float di = __shfl(dc, idx);
            uint4 u = *(const uint4*)(As + (size_t)ci * 32 + part * 8);
            acc[0] = fmaf(di, lo16f(u.x), acc[0]);
            acc[1] = fmaf(di, hi16f(u.x), acc[1]);
            acc[2] = fmaf(di, lo16f(u.y), acc[2]);
            acc[3] = fmaf(di, hi16f(u.y), acc[3]);
            acc[4] = fmaf(di, lo16f(u.z), acc[4]);
            acc[5] = fmaf(di, hi16f(u.z), acc[5]);
            acc[6] = fmaf(di, lo16f(u.w), acc[6]);
            acc[7] = fmaf(di, hi16f(u.w), acc[7]);
        }
    }
    // reduce the 16 replicas (lanes part+4*rep) down to rep 0
#pragma unroll
    for (int o = 4; o < 64; o <<= 1)
#pragma unroll
        for (int i = 0; i < 8; ++i) acc[i] += __shfl_xor(acc[i], o);

    if (rep == 0) {  // lanes 0..3
        uint4 au = *(const uint4*)(As + (size_t)v * 32 + part * 8);
        float av[8] = {lo16f(au.x), hi16f(au.x), lo16f(au.y), hi16f(au.y),
                       lo16f(au.z), hi16f(au.z), lo16f(au.w), hi16f(au.w)};
        unsigned short ov[8];
#pragma unroll
        for (int i = 0; i < 8; ++i)
            ov[i] = f2b(0.5f * dv * (dv * av[i] + acc[i]) + 0.5f * av[i]);
        *(short8*)(Gs + (size_t)v * 32 + part * 8) = *(short8*)ov;
    }
    if (s == 0) {
#pragma unroll
        for (int o = 1; o < 64; o <<= 1) sdc += __shfl_xor(sdc, o);
        if (lane == 0) pv[v] = 0.5f * dv * (dv + sdc) + 0.5f;
    }
}

// ---------------------------------------------------------------------------
// Fused layer GEMM (v4, slab-major A/G): Out = relu(l2norm(A@W + G@Wc + b + pv*bc)).
// K=512; block = 128 rows x 256 cols; wave = 32 rows x 256 cols.
// Register-pipelined B staging through LDS dbuf (conflict-free fragment order).
// A/G fragment loads are fully contiguous 1KB/wave in slab-major layout.
// Epilogue stages slab-major and stores contiguous.
// ---------------------------------------------------------------------------
__global__ __launch_bounds__(256, 2) void gemm512_norm(const unsigned short* __restrict__ A,
                                                       const unsigned short* __restrict__ G,
                                                       const unsigned short* __restrict__ Wp,
                                                       const float* __restrict__ bias,
                                                       const float* __restrict__ biasc,
                                                       const float* __restrict__ pv,
                                                       unsigned short* __restrict__ Out,
                                                       int M) {
    __shared__ unsigned short smem[16384];  // 2 x 8192 B dbuf; epilogue slab-major Cls
    int tid = threadIdx.x, lane = tid & 63, wave = tid >> 6;
    int fr = lane & 15, quad = lane >> 4;
    int rb = blockIdx.x * 128;

    int r0 = rb + wave * 32 + fr;      if (r0 >= M) r0 = M - 1;
    int r1 = rb + wave * 32 + 16 + fr; if (r1 >= M) r1 = M - 1;
    const unsigned short* ap0 = A + (size_t)r0 * 32 + quad * 8;
    const unsigned short* ap1 = A + (size_t)r1 * 32 + quad * 8;
    const unsigned short* gp0 = G + (size_t)r0 * 32 + quad * 8;
    const unsigned short* gp1 = G + (size_t)r1 * 32 + quad * 8;

    float4v acc[2][16];
#pragma unroll
    for (int i = 0; i < 2; ++i)
#pragma unroll
        for (int j = 0; j < 16; ++j) acc[i][j] = (float4v){0.f, 0.f, 0.f, 0.f};

    // kk=0: load to regs, write buf0
    short8 w[4];
#pragma unroll
    for (int i = 0; i < 4; ++i)
        w[i] = *(const short8*)(Wp + (size_t)(i * 256 + tid) * 8);
#pragma unroll
    for (int i = 0; i < 4; ++i)
        *(short8*)&smem[(i * 256 + tid) * 8] = w[i];
    short8 a0c = *(const short8*)ap0;
    short8 a1c = *(const short8*)ap1;

    for (int kk = 0; kk < 16; ++kk) {
        __syncthreads();
        int cur = (kk & 1) * 8192;
        if (kk < 15) {
#pragma unroll
            for (int i = 0; i < 4; ++i)
                w[i] = *(const short8*)(Wp + (size_t)(kk + 1) * 8192 + (size_t)(i * 256 + tid) * 8);
        }
        short8 a0n, a1n;
        if (kk < 15) {
            int kn = kk + 1;
            size_t soff = (size_t)(kn & 7) * NSL;
            a0n = (kn < 8) ? *(const short8*)(ap0 + soff) : *(const short8*)(gp0 + soff);
            a1n = (kn < 8) ? *(const short8*)(ap1 + soff) : *(const short8*)(gp1 + soff);
        }
#pragma unroll
        for (int j = 0; j < 16; ++j) {
            short8 b = *(const short8*)&smem[cur + j * 512 + lane * 8];
            acc[0][j] = __builtin_amdgcn_mfma_f32_16x16x32_bf16(a0c, b, acc[0][j], 0, 0, 0);
            acc[1][j] = __builtin_amdgcn_mfma_f32_16x16x32_bf16(a1c, b, acc[1][j], 0, 0, 0);
        }
        if (kk < 15) {
            int nxt = ((kk + 1) & 1) * 8192;
#pragma unroll
            for (int i = 0; i < 4; ++i)
                *(short8*)&smem[nxt + (i * 256 + tid) * 8] = w[i];
        }
        a0c = a0n;
        a1c = a1n;
    }

    // Epilogue: bias + pv*bc, row L2-norm, relu.
    float bv[16], bcv[16];
#pragma unroll
    for (int j = 0; j < 16; ++j) {
        bv[j] = bias[j * 16 + fr];
        bcv[j] = biasc[j * 16 + fr];
    }
    float pvr[2][4];
#pragma unroll
    for (int i = 0; i < 2; ++i)
#pragma unroll
        for (int r = 0; r < 4; ++r) {
            int rg = rb + wave * 32 + i * 16 + quad * 4 + r;
            if (rg >= M) rg = M - 1;
            pvr[i][r] = pv[rg];
        }
    float ss[2][4] = {{0.f, 0.f, 0.f, 0.f}, {0.f, 0.f, 0.f, 0.f}};
#pragma unroll
    for (int i = 0; i < 2; ++i)
#pragma unroll
        for (int j = 0; j < 16; ++j)
#pragma unroll
            for (int r = 0; r < 4; ++r) {
                float t = acc[i][j][r] + bv[j] + pvr[i][r] * bcv[j];
                acc[i][j][r] = t;
                ss[i][r] = fmaf(t, t, ss[i][r]);
            }
#pragma unroll
    for (int o = 1; o < 16; o <<= 1)
#pragma unroll
        for (int i = 0; i < 2; ++i)
#pragma unroll
            for (int r = 0; r < 4; ++r) ss[i][r] += __shfl_xor(ss[i][r], o);
    float inv[2][4];
#pragma unroll
    for (int i = 0; i < 2; ++i)
#pragma unroll
        for (int r = 0; r < 4; ++r) inv[i][r] = 1.0f / fmaxf(sqrtf(ss[i][r]), 1e-12f);

    // 2 rounds of 64 rows; Cls staged SLAB-MAJOR [8][64][32]; contiguous stores.
#pragma unroll
    for (int rd = 0; rd < 2; ++rd) {
        __syncthreads();
        if ((wave >> 1) == rd) {
#pragma unroll
            for (int i = 0; i < 2; ++i)
#pragma unroll
                for (int j = 0; j < 16; ++j)
#pragma unroll
                    for (int r = 0; r < 4; ++r) {
                        int lrow = (wave & 1) * 32 + i * 16 + quad * 4 + r;
                        smem[(j >> 1) * 2048 + lrow * 32 + (j & 1) * 16 + fr] =
                            f2b(fmaxf(acc[i][j][r] * inv[i][r], 0.f));
                    }
        }
        __syncthreads();
#pragma unroll
        for (int b = 0; b < 8; ++b) {
            int chunk = b * 256 + tid;  // 2048 = 8 slabs x 64 rows x 4 parts
            int slab = chunk >> 8, rw = (chunk >> 2) & 63, pt = chunk & 3;
            int gr = rb + rd * 64 + rw;
            if (gr < M)
                *(short8*)(Out + (size_t)slab * NSL + (size_t)gr * 32 + pt * 8) =
                    *(const short8*)&smem[slab * 2048 + rw * 32 + pt * 8];
        }
    }
}

// ---------------------------------------------------------------------------
// Final projection (MFMA): out[M x 32](fp32) = A(slab-major) @ W2 + b2
// ---------------------------------------------------------------------------
__global__ __launch_bounds__(256) void gemm_final_mfma(const unsigned short* __restrict__ A,
                                                       const unsigned short* __restrict__ Wt2,
                                                       const float* __restrict__ b2,
                                                       float* __restrict__ out, int M) {
    __shared__ unsigned short Als[128 * 32];
    __shared__ unsigned short Bls[32 * 32];
    int tid = threadIdx.x;
    int lane = tid & 63, wave = tid >> 6;
    int rowBase = blockIdx.x * 128;

    float4v acc[2][2];
#pragma unroll
    for (int i = 0; i < 2; ++i)
#pragma unroll
        for (int j = 0; j < 2; ++j) acc[i][j] = (float4v){0.f, 0.f, 0.f, 0.f};

    int sRow = wave * 32 + (lane >> 2);
    int sK = (lane & 3) * 8;
    int fr = lane & 15, fk = (lane >> 4) * 8;
    int bn = tid >> 3, bk4 = (tid & 7) * 4;

    for (int k0 = 0; k0 < 256; k0 += 32) {
        size_t soff = (size_t)(k0 >> 5) * NSL;
        int r0 = rowBase + sRow;       if (r0 >= M) r0 = M - 1;
        int r1 = rowBase + sRow + 16;  if (r1 >= M) r1 = M - 1;
        __builtin_amdgcn_global_load_lds((const AS1 void*)(A + soff + (size_t)r0 * 32 + sK),
                                         (AS3 void*)&Als[(wave * 32) * 32], 16, 0, 0);
        __builtin_amdgcn_global_load_lds((const AS1 void*)(A + soff + (size_t)r1 * 32 + sK),
                                         (AS3 void*)&Als[(wave * 32 + 16) * 32], 16, 0, 0);
        *(ushort4*)&Bls[bn * 32 + bk4] = *(const ushort4*)&Wt2[bn * 256 + k0 + bk4];
        __syncthreads();

        short8 af[2], bfr[2];
#pragma unroll
        for (int i = 0; i < 2; ++i)
            af[i] = *(const short8*)&Als[(wave * 32 + i * 16 + fr) * 32 + fk];
#pragma unroll
        for (int j = 0; j < 2; ++j)
            bfr[j] = *(const short8*)&Bls[(j * 16 + fr) * 32 + fk];
#pragma unroll
        for (int i = 0; i < 2; ++i)
#pragma unroll
            for (int j = 0; j < 2; ++j)
                acc[i][j] = __builtin_amdgcn_mfma_f32_16x16x32_bf16(af[i], bfr[j], acc[i][j], 0, 0, 0);
        __syncthreads();
    }

    int cr = (lane >> 4) * 4, cc = lane & 15;
#pragma unroll
    for (int i = 0; i < 2; ++i) {
#pragma unroll
        for (int j = 0; j < 2; ++j) {
            int colg = j * 16 + cc;
            float bv = b2[colg];
#pragma unroll
            for (int r = 0; r < 4; ++r) {
                int rowg = rowBase + wave * 32 + i * 16 + cr + r;
                if (rowg < M) out[(size_t)rowg * 32 + colg] = acc[i][j][r] + bv;
            }
        }
    }
}

// ---------------------------------------------------------------------------
extern "C" void kernel_launch(void* const* d_in, const int* in_sizes, int n_in,
                              void* d_out, int out_size, void* d_ws, size_t ws_size,
                              hipStream_t stream) {
    const float* x   = (const float*)d_in[0];
    const int* edge  = (const int*)d_in[1];
    const float* W0  = (const float*)d_in[2];
    const float* b0  = (const float*)d_in[3];
    const float* Wn0 = (const float*)d_in[4];
    const float* bn0 = (const float*)d_in[5];
    const float* W1  = (const float*)d_in[6];
    const float* b1  = (const float*)d_in[7];
    const float* Wn1 = (const float*)d_in[8];
    const float* bn1 = (const float*)d_in[9];
    const float* W2  = (const float*)d_in[10];
    const float* b2  = (const float*)d_in[11];
    float* out = (float*)d_out;

    const int N = NN, E = NE;
    const int* row = edge;
    const int* col = edge + E;

    // Workspace layout
    char* p = (char*)d_ws;
    unsigned short* Xbf = (unsigned short*)p; p += (size_t)N * DD * 2;  // slab-major
    unsigned short* Gbf = (unsigned short*)p; p += (size_t)N * DD * 2;  // slab-major
    unsigned short* Abf = (unsigned short*)p; p += (size_t)N * DD * 2;  // slab-major
    unsigned short* Wp0 = (unsigned short*)p; p += 16 * 8192 * 2;  // packed [W0|Wc0]
    unsigned short* Wp1 = (unsigned short*)p; p += 16 * 8192 * 2;  // packed [W1|Wc1]
    unsigned short* Wt2 = (unsigned short*)p; p += 32 * 256 * 2;
    float* bc0   = (float*)p; p += 256 * 4;
    float* bc1   = (float*)p; p += 256 * 4;
    float* pv    = (float*)p; p += (size_t)N * 4;
    int* cnt     = (int*)p; p += (size_t)N * 4;
    int* row_ptr = (int*)p; p += (size_t)(N + 1) * 4;
    int* cursor  = (int*)p; p += (size_t)N * 4;
    float* dinv  = (float*)p; p += (size_t)N * 4;
    int* csr_col = (int*)p; p += (size_t)E * 4;
    float* csr_dc = (float*)p; p += (size_t)E * 4;
    int* bsum    = (int*)p; p += 256 * 4;
    int* bpre    = (int*)p; p += 256 * 4;

    const int nblk = (N + 255) / 256;  // 196
    const int eb = (E + 255) / 256;

    // CSR build
    hipMemsetAsync(cnt, 0, (size_t)N * sizeof(int), stream);
    count_kernel<<<eb, 256, 0, stream>>>(row, cnt, E);
    block_sums<<<nblk, 256, 0, stream>>>(cnt, bsum, N);
    scan_bsums<<<1, 256, 0, stream>>>(bsum, bpre, nblk);
    fill_rowptr<<<nblk, 256, 0, stream>>>(cnt, bpre, row_ptr, cursor, dinv, N, E);
    scatter_kernel<<<eb, 256, 0, stream>>>(row, col, cursor, dinv, csr_col, csr_dc, E);

    // casts + packed weights + composed bias
    cast_x_slab<<<(N + 63) / 64, 256, 0, stream>>>(x, Xbf);
    cast_w2<<<32, 256, 0, stream>>>(W2, Wt2);
    compose_wc<<<dim3(256, 2), 256, 0, stream>>>(W0, Wn0, W1, Wn1, Wp0, Wp1);
    compose_bc<<<dim3(1, 2), 256, 0, stream>>>(b0, Wn0, bn0, b1, Wn1, bn1, bc0, bc1);

    const int gTiles = (N + 127) / 128;  // 391
    dim3 ga(N / 4, 8);
    // Layer 1
    agg_g_slab<<<ga, 256, 0, stream>>>(Xbf, dinv, row_ptr, csr_col, csr_dc, Gbf, pv);
    gemm512_norm<<<gTiles, 256, 0, stream>>>(Xbf, Gbf, Wp0, b0, bc0, pv, Abf, N);
    // Layer 2
    agg_g_slab<<<ga, 256, 0, stream>>>(Abf, dinv, row_ptr, csr_col, csr_dc, Gbf, pv);
    gemm512_norm<<<gTiles, 256, 0, stream>>>(Abf, Gbf, Wp1, b1, bc1, pv, Xbf, N);
    // Final projection
    gemm_final_mfma<<<gTiles, 256, 0, stream>>>(Xbf, Wt2, b2, out, N);
}